// Round 2
// baseline (1260.048 us; speedup 1.0000x reference)
//
#include <hip/hip_runtime.h>
#include <math.h>

#define N_TOK 131072
#define K_CB  1024
#define D_DIM 64
#define CHUNK 32   // codes per K-chunk: 32 accumulators live, x re-read once per chunk

// Precompute ||e_k||^2 for all K codebook rows into workspace.
__global__ void en_sq_kernel(const float* __restrict__ emb, float* __restrict__ en) {
    int k = blockIdx.x * blockDim.x + threadIdx.x;
    if (k < K_CB) {
        float s = 0.f;
        #pragma unroll
        for (int d = 0; d < D_DIM; ++d) {
            float v = emb[k * D_DIM + d];
            s = fmaf(v, v, s);
        }
        en[k] = s;
    }
}

// One thread per row. K processed in chunks of 32 codes; D sliced in 4x16 so
// per-thread live state stays ~70 VGPR (no spill/remat possible). emb/en reads
// are wave-uniform -> scalar loads (SGPR broadcast, no VGPR cost).
__global__ __launch_bounds__(256)
void vq_argmin_write_kernel(const float* __restrict__ x,
                            const float* __restrict__ emb,
                            const float* __restrict__ en,
                            float* __restrict__ zq,
                            float* __restrict__ probs) {
    const int tid = threadIdx.x;
    const int base_row = blockIdx.x * 256;
    const int row = base_row + tid;
    const float4* __restrict__ xrow4 = (const float4*)(x + (size_t)row * D_DIM);

    // ||x||^2 pre-pass (streams the row once; lives only in this loop).
    float xn = 0.f;
    #pragma unroll
    for (int i = 0; i < D_DIM / 4; ++i) {
        float4 v = xrow4[i];
        xn = fmaf(v.x, v.x, xn);
        xn = fmaf(v.y, v.y, xn);
        xn = fmaf(v.z, v.z, xn);
        xn = fmaf(v.w, v.w, xn);
    }

    float best = INFINITY;
    int bestk = 0;

    for (int kb = 0; kb < K_CB; kb += CHUNK) {
        float acc[CHUNK];
        #pragma unroll
        for (int c = 0; c < CHUNK; ++c) acc[c] = 0.f;

        #pragma unroll
        for (int ds = 0; ds < 4; ++ds) {          // 16-element D-slice
            const float4 xv0 = xrow4[ds * 4 + 0];
            const float4 xv1 = xrow4[ds * 4 + 1];
            const float4 xv2 = xrow4[ds * 4 + 2];
            const float4 xv3 = xrow4[ds * 4 + 3];
            #pragma unroll
            for (int c = 0; c < CHUNK; ++c) {
                // wave-uniform address -> s_load (scalar broadcast)
                const float* __restrict__ er = emb + (size_t)(kb + c) * D_DIM + ds * 16;
                float a = acc[c];
                a = fmaf(xv0.x, er[0],  a);
                a = fmaf(xv0.y, er[1],  a);
                a = fmaf(xv0.z, er[2],  a);
                a = fmaf(xv0.w, er[3],  a);
                a = fmaf(xv1.x, er[4],  a);
                a = fmaf(xv1.y, er[5],  a);
                a = fmaf(xv1.z, er[6],  a);
                a = fmaf(xv1.w, er[7],  a);
                a = fmaf(xv2.x, er[8],  a);
                a = fmaf(xv2.y, er[9],  a);
                a = fmaf(xv2.z, er[10], a);
                a = fmaf(xv2.w, er[11], a);
                a = fmaf(xv3.x, er[12], a);
                a = fmaf(xv3.y, er[13], a);
                a = fmaf(xv3.z, er[14], a);
                a = fmaf(xv3.w, er[15], a);
                acc[c] = a;
            }
        }

        #pragma unroll
        for (int c = 0; c < CHUNK; ++c) {
            // matches reference rounding: round(xn+en), then single-rounded
            // subtract of 2*dot via fma
            float dist = fmaf(-2.f, acc[c], xn + en[kb + c]);
            if (dist < best) { best = dist; bestk = kb + c; }  // strict <: first-min
        }
    }

    __shared__ int bk_lds[256];
    bk_lds[tid] = bestk;
    __syncthreads();

    // z_q: 256 rows x 16 float4 per block; coalesced stores, gather from
    // L2-resident codebook (256 KB).
    for (int i = tid; i < 256 * (D_DIM / 4); i += 256) {
        int r = i >> 4;
        int c = i & 15;
        int kk = bk_lds[r];
        float4 v = ((const float4*)(emb + (size_t)kk * D_DIM))[c];
        ((float4*)(zq + (size_t)(base_row + r) * D_DIM))[c] = v;
    }

    // probs: row j is 1024 floats = 256 float4; thread tid writes float4 #tid
    // of each row -> fully coalesced 1 KiB/wave stores.
    for (int j = 0; j < 256; ++j) {
        int kk = bk_lds[j];
        int c = tid * 4;
        float4 v;
        v.x = (kk == c    ) ? 1.f : 0.f;
        v.y = (kk == c + 1) ? 1.f : 0.f;
        v.z = (kk == c + 2) ? 1.f : 0.f;
        v.w = (kk == c + 3) ? 1.f : 0.f;
        ((float4*)(probs + (size_t)(base_row + j) * K_CB))[tid] = v;
    }
}

extern "C" void kernel_launch(void* const* d_in, const int* in_sizes, int n_in,
                              void* d_out, int out_size, void* d_ws, size_t ws_size,
                              hipStream_t stream) {
    const float* x   = (const float*)d_in[0];   // [N, D] fp32
    const float* emb = (const float*)d_in[1];   // [K, D] fp32
    float* zq    = (float*)d_out;                              // [N, D]
    float* probs = (float*)d_out + (size_t)N_TOK * D_DIM;      // [N, K]
    float* en    = (float*)d_ws;                               // [K]

    en_sq_kernel<<<(K_CB + 255) / 256, 256, 0, stream>>>(emb, en);
    vq_argmin_write_kernel<<<N_TOK / 256, 256, 0, stream>>>(x, emb, en, zq, probs);
}

// Round 4
// 764.431 us; speedup vs baseline: 1.6483x; 1.6483x over previous
//
#include <hip/hip_runtime.h>
#include <math.h>

#define N_TOK 131072
#define K_CB  1024
#define D_DIM 64
#define MARGIN 0.0625f

// ws layout: en[1024] f32 @0 ; esplit[1024*128] bf16 @4096 ; fixcnt @266240 ; fixlist @266248
#define WS_EN     0
#define WS_ES     4096
#define WS_CNT    266240
#define WS_LIST   266248

typedef short bf16x8 __attribute__((ext_vector_type(8)));
typedef float f32x4  __attribute__((ext_vector_type(4)));

__device__ __forceinline__ ushort f2bf(float f) {   // RNE fp32->bf16
    uint u = __float_as_uint(f);
    u += 0x7FFFu + ((u >> 16) & 1u);
    return (ushort)(u >> 16);
}
__device__ __forceinline__ float bf2f(ushort h) {
    return __uint_as_float(((uint)h) << 16);
}

// ---- prep: en[k] = ||e_k||^2 (exact R1 rounding), esplit = [hi(64) | lo(64)] bf16 per code ----
__global__ void prep_kernel(const float* __restrict__ emb, float* __restrict__ en,
                            ushort* __restrict__ es, uint* __restrict__ fixcnt) {
    int k = blockIdx.x * blockDim.x + threadIdx.x;
    if (k == 0 && blockIdx.x == 0) *fixcnt = 0;
    if (k < K_CB) {
        float s = 0.f;
        #pragma unroll
        for (int d = 0; d < D_DIM; ++d) {
            float v = emb[k * D_DIM + d];
            s = fmaf(v, v, s);
        }
        en[k] = s;
        #pragma unroll
        for (int d = 0; d < D_DIM; ++d) {
            float f = emb[k * D_DIM + d];
            ushort h = f2bf(f);
            es[(size_t)k * 128 + d]      = h;
            es[(size_t)k * 128 + 64 + d] = f2bf(f - bf2f(h));
        }
    }
}

// ---- main: split-bf16 MFMA distance GEMM (hi*hi + hi*lo + lo*hi) + top-2 argmin + fused writes ----
// block = 256 thr = 4 waves; block tile = 128 rows; wave tile = 32 rows x (1024 codes in 16-code chunks)
__global__ __launch_bounds__(256) void vq_main(
    const float* __restrict__ x, const float* __restrict__ emb,
    const float* __restrict__ en, const ushort* __restrict__ es,
    float* __restrict__ zq, float* __restrict__ probs,
    uint* __restrict__ fixcnt, uint* __restrict__ fixlist, uint fixcap)
{
    const int tid  = threadIdx.x;
    const int wave = tid >> 6, lane = tid & 63;
    const int quad = lane >> 4, l15 = lane & 15;
    const int blockRow = blockIdx.x * 128;
    const int waveRow  = blockRow + wave * 32;

    __shared__ uint lds_k[128];

    // A-frags per row-group g: [0]=hi d0..31, [1]=hi d32..63, [2]=lo d0..31, [3]=lo d32..63.
    // A layout (m120): A[m=lane&15][k=quad*8+j].
    bf16x8 af[2][4];
    #pragma unroll
    for (int g = 0; g < 2; ++g) {
        const float* xr = x + (size_t)(waveRow + g * 16 + l15) * D_DIM + quad * 8;
        f32x4 p0 = *(const f32x4*)(xr);
        f32x4 p1 = *(const f32x4*)(xr + 4);
        f32x4 p2 = *(const f32x4*)(xr + 32);
        f32x4 p3 = *(const f32x4*)(xr + 36);
        float v0[8], v1[8];
        #pragma unroll
        for (int j = 0; j < 4; ++j) { v0[j] = p0[j]; v0[4 + j] = p1[j]; v1[j] = p2[j]; v1[4 + j] = p3[j]; }
        #pragma unroll
        for (int j = 0; j < 8; ++j) {
            ushort h0 = f2bf(v0[j]);
            af[g][0][j] = (short)h0;
            af[g][2][j] = (short)f2bf(v0[j] - bf2f(h0));
            ushort h1 = f2bf(v1[j]);
            af[g][1][j] = (short)h1;
            af[g][3][j] = (short)f2bf(v1[j] - bf2f(h1));
        }
    }

    float b1[8], b2[8]; int k1[8];
    #pragma unroll
    for (int s = 0; s < 8; ++s) { b1[s] = INFINITY; b2[s] = INFINITY; k1[s] = 0; }

    const bf16x8* __restrict__ esv = (const bf16x8*)es;  // 16 frags per code row

    for (int cb = 0; cb < 64; ++cb) {
        const int code = cb * 16 + l15;
        // B-frags: B[k=quad*8+j][n=lane&15]; bfr[0]=hi d0..31, [1]=hi d32..63, [2]=lo d0..31, [3]=lo d32..63
        bf16x8 bfr[4];
        #pragma unroll
        for (int ks = 0; ks < 4; ++ks) bfr[ks] = esv[(size_t)code * 16 + ks * 4 + quad];

        f32x4 acc0 = {0.f, 0.f, 0.f, 0.f};
        f32x4 acc1 = {0.f, 0.f, 0.f, 0.f};
        // dot = xh*eh + xh*el + xl*eh  (xl*el ~1e-4, absorbed by MARGIN)
        acc0 = __builtin_amdgcn_mfma_f32_16x16x32_bf16(af[0][0], bfr[0], acc0, 0, 0, 0);
        acc0 = __builtin_amdgcn_mfma_f32_16x16x32_bf16(af[0][1], bfr[1], acc0, 0, 0, 0);
        acc0 = __builtin_amdgcn_mfma_f32_16x16x32_bf16(af[0][0], bfr[2], acc0, 0, 0, 0);
        acc0 = __builtin_amdgcn_mfma_f32_16x16x32_bf16(af[0][1], bfr[3], acc0, 0, 0, 0);
        acc0 = __builtin_amdgcn_mfma_f32_16x16x32_bf16(af[0][2], bfr[0], acc0, 0, 0, 0);
        acc0 = __builtin_amdgcn_mfma_f32_16x16x32_bf16(af[0][3], bfr[1], acc0, 0, 0, 0);
        acc1 = __builtin_amdgcn_mfma_f32_16x16x32_bf16(af[1][0], bfr[0], acc1, 0, 0, 0);
        acc1 = __builtin_amdgcn_mfma_f32_16x16x32_bf16(af[1][1], bfr[1], acc1, 0, 0, 0);
        acc1 = __builtin_amdgcn_mfma_f32_16x16x32_bf16(af[1][0], bfr[2], acc1, 0, 0, 0);
        acc1 = __builtin_amdgcn_mfma_f32_16x16x32_bf16(af[1][1], bfr[3], acc1, 0, 0, 0);
        acc1 = __builtin_amdgcn_mfma_f32_16x16x32_bf16(af[1][2], bfr[0], acc1, 0, 0, 0);
        acc1 = __builtin_amdgcn_mfma_f32_16x16x32_bf16(af[1][3], bfr[1], acc1, 0, 0, 0);

        const float env = en[code];
        // C layout (m89): col = lane&15 (this lane's code), row = quad*4 + reg.
        #pragma unroll
        for (int r = 0; r < 4; ++r) {
            {
                float d = fmaf(-2.f, acc0[r], env);
                bool lt = d < b1[r];
                b2[r] = lt ? b1[r] : fminf(b2[r], d);
                k1[r] = lt ? code : k1[r];
                b1[r] = lt ? d : b1[r];
            }
            {
                int s = 4 + r;
                float d = fmaf(-2.f, acc1[r], env);
                bool lt = d < b1[s];
                b2[s] = lt ? b1[s] : fminf(b2[s], d);
                k1[s] = lt ? code : k1[s];
                b1[s] = lt ? d : b1[s];
            }
        }
    }

    // cross-lane top-2 merge over the 16 lanes holding one row's columns
    #pragma unroll
    for (int s = 0; s < 8; ++s) {
        #pragma unroll
        for (int off = 1; off < 16; off <<= 1) {
            float ob1 = __shfl_xor(b1[s], off);
            int   ok1 = __shfl_xor(k1[s], off);
            float ob2 = __shfl_xor(b2[s], off);
            bool better = (ob1 < b1[s]) || (ob1 == b1[s] && ok1 < k1[s]);
            float loser = better ? b1[s] : ob1;
            b1[s] = better ? ob1 : b1[s];
            k1[s] = better ? ok1 : k1[s];
            b2[s] = fminf(fminf(b2[s], ob2), loser);
        }
    }
    if (l15 == 0) {
        #pragma unroll
        for (int s = 0; s < 8; ++s) {
            int g = s >> 2, r = s & 3;
            int lrow = wave * 32 + g * 16 + quad * 4 + r;
            uint word = (uint)k1[s];
            if (b2[s] - b1[s] <= MARGIN) word |= 0x80000000u;   // uncertain -> fixup
            lds_k[lrow] = word;
        }
    }
    __syncthreads();

    // fixup append (best-guess written below; fixup kernel rewrites if needed)
    if (tid < 128) {
        uint w = lds_k[tid];
        if (w & 0x80000000u) {
            uint idx = atomicAdd(fixcnt, 1u);
            if (idx < fixcap) fixlist[idx] = (uint)(blockRow + tid) | ((w & 0x3FFu) << 17);
        }
    }

    // z_q: 128 rows x 16 float4, gather from original fp32 emb (exact copy)
    #pragma unroll
    for (int t = 0; t < 8; ++t) {
        int i = tid + t * 256;
        int r = i >> 4, c = i & 15;
        int kk = (int)(lds_k[r] & 0x3FFu);
        f32x4 v = ((const f32x4*)(emb + (size_t)kk * D_DIM))[c];
        __builtin_nontemporal_store(v, (f32x4*)(zq + (size_t)(blockRow + r) * D_DIM) + c);
    }

    // probs: one float4 per thread per row, fully coalesced
    for (int j = 0; j < 128; ++j) {
        int kk = (int)(lds_k[j] & 0x3FFu);
        int c = tid * 4;
        f32x4 v;
        v[0] = (kk == c    ) ? 1.f : 0.f;
        v[1] = (kk == c + 1) ? 1.f : 0.f;
        v[2] = (kk == c + 2) ? 1.f : 0.f;
        v[3] = (kk == c + 3) ? 1.f : 0.f;
        __builtin_nontemporal_store(v, (f32x4*)(probs + (size_t)(blockRow + j) * K_CB) + tid);
    }
}

// ---- fixup: exact fp32 re-argmin (bit-identical to the R1/R2 formula) for flagged rows ----
__global__ __launch_bounds__(256) void vq_fixup(
    const float* __restrict__ x, const float* __restrict__ emb,
    const float* __restrict__ en,
    float* __restrict__ zq, float* __restrict__ probs,
    const uint* __restrict__ fixcnt, const uint* __restrict__ fixlist, uint fixcap)
{
    const int lane = threadIdx.x & 63;
    const uint gwave = (uint)((blockIdx.x * 256 + threadIdx.x) >> 6);
    uint cnt = *fixcnt;
    if (cnt > fixcap) cnt = fixcap;

    for (uint e = gwave; e < cnt; e += 1024u) {
        uint w = fixlist[e];
        int row = (int)(w & 0x1FFFFu);
        int kg  = (int)(w >> 17);
        const float* xr = x + (size_t)row * D_DIM;
        float xn = 0.f;
        #pragma unroll
        for (int d = 0; d < D_DIM; ++d) xn = fmaf(xr[d], xr[d], xn);

        float bd = INFINITY; int bk = 0;
        for (int t = 0; t < 16; ++t) {
            int code = t * 64 + lane;                 // ascending per lane
            const float* er = emb + (size_t)code * D_DIM;
            float a0 = 0.f, a1 = 0.f, a2 = 0.f, a3 = 0.f;
            #pragma unroll
            for (int d = 0; d < D_DIM; d += 4) {
                a0 = fmaf(xr[d + 0], er[d + 0], a0);
                a1 = fmaf(xr[d + 1], er[d + 1], a1);
                a2 = fmaf(xr[d + 2], er[d + 2], a2);
                a3 = fmaf(xr[d + 3], er[d + 3], a3);
            }
            float acc = (a0 + a1) + (a2 + a3);
            float dist = fmaf(-2.f, acc, xn + en[code]);
            if (dist < bd) { bd = dist; bk = code; }
        }
        #pragma unroll
        for (int off = 1; off < 64; off <<= 1) {
            float od = __shfl_xor(bd, off);
            int   ok = __shfl_xor(bk, off);
            if (od < bd || (od == bd && ok < bk)) { bd = od; bk = ok; }
        }
        if (bk != kg) {
            if (lane == 0) {
                probs[(size_t)row * K_CB + kg] = 0.f;
                probs[(size_t)row * K_CB + bk] = 1.f;
            }
            if (lane < 16)
                ((f32x4*)(zq + (size_t)row * D_DIM))[lane] =
                    ((const f32x4*)(emb + (size_t)bk * D_DIM))[lane];
        }
    }
}

extern "C" void kernel_launch(void* const* d_in, const int* in_sizes, int n_in,
                              void* d_out, int out_size, void* d_ws, size_t ws_size,
                              hipStream_t stream) {
    const float* x   = (const float*)d_in[0];   // [N, D] fp32
    const float* emb = (const float*)d_in[1];   // [K, D] fp32
    float* zq    = (float*)d_out;                              // [N, D]
    float* probs = (float*)d_out + (size_t)N_TOK * D_DIM;      // [N, K]

    char* ws = (char*)d_ws;
    float*  en      = (float*)(ws + WS_EN);
    ushort* es      = (ushort*)(ws + WS_ES);
    uint*   fixcnt  = (uint*)(ws + WS_CNT);
    uint*   fixlist = (uint*)(ws + WS_LIST);
    uint fixcap = (ws_size > WS_LIST + 4) ? (uint)((ws_size - WS_LIST) / 4) : 0u;

    prep_kernel<<<K_CB / 256, 256, 0, stream>>>(emb, en, es, fixcnt);
    vq_main<<<N_TOK / 128, 256, 0, stream>>>(x, emb, en, es, zq, probs, fixcnt, fixlist, fixcap);
    vq_fixup<<<256, 256, 0, stream>>>(x, emb, en, zq, probs, fixcnt, fixlist, fixcap);
}